// Round 1
// 901.771 us; speedup vs baseline: 1.0695x; 1.0695x over previous
//
#include <hip/hip_runtime.h>
#include <hip/hip_bf16.h>

// Grid LSTM (tanh grid-RNN), D=2, S=T=48, B=32, H=256. f32 in/out; bf16 MFMA
// internally. Persistent systolic columns, one block per (d, t) walking s.
// v2: nh halves merged into 512-thread blocks -> the "up" operand lives in a
// persistent LDS image (no global round-trip, no up flag). Single left-flag
// wait per cell, flags padded to one per 128B LLC line, per-wave early flag
// adds (each wave drains its own bypass stores, then signals; block barriers
// happen after the signal, off the inter-block critical path).
// Handoff protocol unchanged: producers write h via cache-bypassing agent
// atomic stores (-> LLC), order with s_waitcnt vmcnt(0), then relaxed flag
// add; consumers poll relaxed and read with plain cached loads (each staged
// address read once per block per launch).

typedef short short8 __attribute__((ext_vector_type(8)));
typedef float f32x4 __attribute__((ext_vector_type(4)));

static constexpr size_t UF_OFF    = 0;                          // 512 KiB U frags (bf16)
static constexpr size_t WF_OFF    = 512u * 1024;                // 256 KiB W frags (bf16)
static constexpr size_t SRCW_OFF  = 768u * 1024;                // 1.5 MiB f32
static constexpr size_t TRGW_OFF  = SRCW_OFF + 48u * 32 * 256 * 4;
static constexpr size_t FLAG0_OFF = TRGW_OFF + 48u * 32 * 256 * 4;
static constexpr size_t FLAG1_OFF = FLAG0_OFF + 48u * 48 * 128;
static constexpr int    FSTRIDE   = 32;  // ints: one flag per 128B line

#define MFMA16(a, b, c) __builtin_amdgcn_mfma_f32_16x16x32_bf16(a, b, c, 0, 0, 0)

__device__ __forceinline__ short f2bf(float f) {
  __hip_bfloat16 h = __float2bfloat16(f);
  return __builtin_bit_cast(short, h);
}

__device__ __forceinline__ size_t plane_off(int d, int s, int t, int c) {
  return (size_t)(((d * 48 + s) * 48 + t) * 2 + c) * 8192u;  // f32 elements
}

__device__ __forceinline__ void wait_ge(int* p, int v) {
  while (__hip_atomic_load(p, __ATOMIC_RELAXED, __HIP_MEMORY_SCOPE_AGENT) < v)
    __builtin_amdgcn_s_sleep(1);
  asm volatile("" ::: "memory");  // keep subsequent loads below the spin
}

// write-through to LLC (sc0 sc1): visible agent-wide once vmcnt retires.
__device__ __forceinline__ void st_llc(float* p, float v) {
  __hip_atomic_store(p, v, __ATOMIC_RELAXED, __HIP_MEMORY_SCOPE_AGENT);
}

__device__ __forceinline__ float fast_tanh(float x) {
  float e = exp2f(x * 2.88539008f);
  return 1.f - __fdividef(2.f, e + 1.f);
}

// ---------------------------------------------------------------------------
// Kernel 1: U (2,512,256) f32 and W (2,256,256) f32 -> bf16 MFMA B-fragments.
// ---------------------------------------------------------------------------
__global__ void preswizzle(const float* __restrict__ U,
                           const float* __restrict__ W,
                           char* __restrict__ ws) {
  int gid = blockIdx.x * 256 + threadIdx.x;
  if (gid < 32768) {  // U
    int r = gid >> 11;
    int d = r >> 3, nh = (r >> 2) & 1, w = r & 3;
    int c = gid & 2047;
    int f = c >> 6, lane = c & 63;
    int nt = f >> 4, ks = f & 15;
    int kbase = ks * 32 + (lane >> 4) * 8;
    int n = nh * 128 + w * 32 + nt * 16 + (lane & 15);
    const float* sp = U + (size_t)d * 512 * 256 + n;
    short8 v;
#pragma unroll
    for (int j = 0; j < 8; ++j) v[j] = f2bf(sp[(size_t)(kbase + j) * 256]);
    *(short8*)(ws + UF_OFF + (size_t)gid * 16) = v;
  } else {            // W
    int idx = gid - 32768;
    int r = idx >> 10;
    int d = r >> 3, nh = (r >> 2) & 1, w = r & 3;
    int c = idx & 1023;
    int f = c >> 6, lane = c & 63;
    int nt = f >> 3, ks = f & 7;
    int kbase = ks * 32 + (lane >> 4) * 8;
    int n = nh * 128 + w * 32 + nt * 16 + (lane & 15);
    const float* sp = W + (size_t)d * 256 * 256 + n;
    short8 v;
#pragma unroll
    for (int j = 0; j < 8; ++j) v[j] = f2bf(sp[(size_t)(kbase + j) * 256]);
    *(short8*)(ws + WF_OFF + (size_t)idx * 16) = v;
  }
}

// ---------------------------------------------------------------------------
// Kernel 2: SRCW[s] = src[s]@W0 + b0 ; TRGW[t] = trg[t]@W0 + b0  (f32)
// ---------------------------------------------------------------------------
__global__ __launch_bounds__(256, 1) void precompute_xw(
    const float* __restrict__ src, const float* __restrict__ trg,
    const float* __restrict__ bvec, char* __restrict__ ws) {
  __shared__ __align__(16) char lds[32 * 528];
  const int bid = blockIdx.x;
  const int i = bid >> 1, nh = bid & 1;
  const int tid = threadIdx.x;
  const int w = tid >> 6, lane = tid & 63;
  const int alane = lane & 15, q = lane >> 4;

  short8 bw[2][8];
  {
    const char* wb = ws + WF_OFF + (size_t)(nh * 4 + w) * 16384u + (size_t)lane * 16;
#pragma unroll
    for (int nt = 0; nt < 2; ++nt)
#pragma unroll
      for (int ks = 0; ks < 8; ++ks)
        bw[nt][ks] = *(const short8*)(wb + (nt * 8 + ks) * 1024);
  }

  const float* plane = (i < 48) ? src + (size_t)i * 8192 : trg + (size_t)(i - 48) * 8192;
#pragma unroll
  for (int it = 0; it < 4; ++it) {
    int gid = it * 256 + tid;
    int row = gid >> 5, c = gid & 31;
    const float* p = plane + row * 256 + c * 8;
    short8 v;
#pragma unroll
    for (int j = 0; j < 8; ++j) v[j] = f2bf(p[j]);
    *(short8*)(lds + row * 528 + c * 16) = v;
  }
  __syncthreads();

  const f32x4 zf = {0.f, 0.f, 0.f, 0.f};
  f32x4 acc[2][2];
  acc[0][0] = zf; acc[0][1] = zf; acc[1][0] = zf; acc[1][1] = zf;
  const char* ar0 = lds + alane * 528 + q * 16;
  const char* ar1 = lds + (alane + 16) * 528 + q * 16;
#pragma unroll
  for (int ks = 0; ks < 8; ++ks) {
    short8 a0 = *(const short8*)(ar0 + ks * 64);
    short8 a1 = *(const short8*)(ar1 + ks * 64);
#pragma unroll
    for (int nt = 0; nt < 2; ++nt) {
      acc[0][nt] = MFMA16(a0, bw[nt][ks], acc[0][nt]);
      acc[1][nt] = MFMA16(a1, bw[nt][ks], acc[1][nt]);
    }
  }

  const int n0 = nh * 128 + w * 32 + alane;
  float bs[2] = {bvec[n0], bvec[n0 + 16]};
  float* dst = (float*)(ws + (i < 48 ? SRCW_OFF : TRGW_OFF)) +
               (size_t)(i < 48 ? i : i - 48) * 8192;
#pragma unroll
  for (int mt = 0; mt < 2; ++mt)
#pragma unroll
    for (int nt = 0; nt < 2; ++nt)
#pragma unroll
      for (int rr = 0; rr < 4; ++rr) {
        int row = mt * 16 + q * 4 + rr;
        dst[row * 256 + n0 + nt * 16] = acc[mt][nt][rr] + bs[nt];
      }
}

// ---------------------------------------------------------------------------
// Kernel 3: persistent systolic grid. 96 blocks x 512 threads = (d, t).
// ---------------------------------------------------------------------------
__global__ __launch_bounds__(512, 2) void grid_main(
    float* __restrict__ out, const float* __restrict__ bvec,
    char* __restrict__ ws) {
  // buf0 = persistent up-image (bf16), buf1/buf2 = staged operand images.
  // Row stride 528B: 16B-aligned, spreads the b128 fragment reads over banks.
  __shared__ __align__(16) char lds[3 * 32 * 528];
  char* const buf0 = lds;
  char* const buf1 = lds + 32 * 528;
  char* const buf2 = lds + 2 * 32 * 528;

  const int bid = blockIdx.x;        // 96 = (d, t)
  const int d = bid / 48;
  const int t = bid % 48;
  const int tid = threadIdx.x;       // 0..511
  const int wv = tid >> 6;           // 0..7
  const int nh = wv >> 2, w = wv & 3;
  const int lane = tid & 63;
  const int alane = lane & 15, q = lane >> 4;
  const int n0 = nh * 128 + w * 32 + alane;

  int* flag0 = (int*)(ws + FLAG0_OFF);
  int* flag1 = (int*)(ws + FLAG1_OFF);
  const float* SRCW = (const float*)(ws + SRCW_OFF);
  const float* TRGW = (const float*)(ws + TRGW_OFF);

  // zero the up-image: s=0 up operand = 0
  for (int i = tid; i < 32 * 528 / 4; i += 512) ((int*)buf0)[i] = 0;

  // U B-frags in registers: bu[nt][ks]; ks 0..7 = Ux (up), 8..15 = Uy (left)
  short8 bu[2][16];
  {
    const char* ub = ws + UF_OFF + (size_t)((d * 2 + nh) * 4 + w) * 32768u +
                     (size_t)lane * 16;
#pragma unroll
    for (int nt = 0; nt < 2; ++nt)
#pragma unroll
      for (int ks = 0; ks < 16; ++ks)
        bu[nt][ks] = *(const short8*)(ub + (nt * 16 + ks) * 1024);
  }

  const char* up0 = buf0 + alane * 528 + q * 16;
  const char* up1 = buf0 + (alane + 16) * 528 + q * 16;
  const char* l0  = buf1 + alane * 528 + q * 16;
  const char* l1  = buf1 + (alane + 16) * 528 + q * 16;
  const char* y0  = buf2 + alane * 528 + q * 16;
  const char* y1  = buf2 + (alane + 16) * 528 + q * 16;

  __syncthreads();  // buf0 zeroed

  if (d == 0) {
    // TRGW[t] row is constant over s: cache in registers once.
    float pfy[16];
    {
      const float* syp = TRGW + (size_t)t * 8192;
#pragma unroll
      for (int mt = 0; mt < 2; ++mt)
#pragma unroll
        for (int nt = 0; nt < 2; ++nt)
#pragma unroll
          for (int rr = 0; rr < 4; ++rr) {
            int row = mt * 16 + q * 4 + rr;
            pfy[(mt * 2 + nt) * 4 + rr] = syp[row * 256 + n0 + nt * 16];
          }
    }
    for (int s = 0; s < 48; ++s) {
      // C-init: accx = x@W0+b0 (SRCW, loaded before the wait), accy = y@W0+b0.
      f32x4 accx[2][2], accy[2][2];
      {
        const float* sxp = SRCW + (size_t)s * 8192;
#pragma unroll
        for (int mt = 0; mt < 2; ++mt)
#pragma unroll
          for (int nt = 0; nt < 2; ++nt)
#pragma unroll
            for (int rr = 0; rr < 4; ++rr) {
              int row = mt * 16 + q * 4 + rr;
              accx[mt][nt][rr] = sxp[row * 256 + n0 + nt * 16];
              accy[mt][nt][rr] = pfy[(mt * 2 + nt) * 4 + rr];
            }
      }
      if (t > 0) {
        wait_ge(&flag0[(s * 48 + (t - 1)) * FSTRIDE], 8);
        const float* pl = out + plane_off(0, s, t - 1, 0);
#pragma unroll
        for (int it = 0; it < 2; ++it) {
          int gid = it * 512 + tid;
          int row = gid >> 5, c = gid & 31;
          const float* p = pl + row * 256 + c * 8;
          short8 v;
#pragma unroll
          for (int j = 0; j < 8; ++j) v[j] = f2bf(p[j]);
          *(short8*)(buf1 + row * 528 + c * 16) = v;
        }
      }
      __syncthreads();
      // T = up@Ux (+ left@Uy), accumulated into both accx and accy.
#pragma unroll
      for (int ks = 0; ks < 8; ++ks) {
        short8 a0 = *(const short8*)(up0 + ks * 64);
        short8 a1 = *(const short8*)(up1 + ks * 64);
        accx[0][0] = MFMA16(a0, bu[0][ks], accx[0][0]);
        accx[0][1] = MFMA16(a0, bu[1][ks], accx[0][1]);
        accx[1][0] = MFMA16(a1, bu[0][ks], accx[1][0]);
        accx[1][1] = MFMA16(a1, bu[1][ks], accx[1][1]);
        accy[0][0] = MFMA16(a0, bu[0][ks], accy[0][0]);
        accy[0][1] = MFMA16(a0, bu[1][ks], accy[0][1]);
        accy[1][0] = MFMA16(a1, bu[0][ks], accy[1][0]);
        accy[1][1] = MFMA16(a1, bu[1][ks], accy[1][1]);
      }
      if (t > 0) {
#pragma unroll
        for (int ks = 0; ks < 8; ++ks) {
          short8 a0 = *(const short8*)(l0 + ks * 64);
          short8 a1 = *(const short8*)(l1 + ks * 64);
          accx[0][0] = MFMA16(a0, bu[0][8 + ks], accx[0][0]);
          accx[0][1] = MFMA16(a0, bu[1][8 + ks], accx[0][1]);
          accx[1][0] = MFMA16(a1, bu[0][8 + ks], accx[1][0]);
          accx[1][1] = MFMA16(a1, bu[1][8 + ks], accx[1][1]);
          accy[0][0] = MFMA16(a0, bu[0][8 + ks], accy[0][0]);
          accy[0][1] = MFMA16(a0, bu[1][8 + ks], accy[0][1]);
          accy[1][0] = MFMA16(a1, bu[0][8 + ks], accy[1][0]);
          accy[1][1] = MFMA16(a1, bu[1][8 + ks], accy[1][1]);
        }
      }
      // Epilogue: tanh, bypass-store both planes (hx0 & hy0 are both consumed).
      float hx[16];
      {
        float* hxp = out + plane_off(0, s, t, 0);
        float* hyp = out + plane_off(0, s, t, 1);
#pragma unroll
        for (int mt = 0; mt < 2; ++mt)
#pragma unroll
          for (int nt = 0; nt < 2; ++nt)
#pragma unroll
            for (int rr = 0; rr < 4; ++rr) {
              int row = mt * 16 + q * 4 + rr;
              int n = n0 + nt * 16;
              float xv = fast_tanh(accx[mt][nt][rr]);
              float yv = fast_tanh(accy[mt][nt][rr]);
              hx[(mt * 2 + nt) * 4 + rr] = xv;
              st_llc(&hxp[row * 256 + n], xv);
              st_llc(&hyp[row * 256 + n], yv);
            }
      }
      // Per-wave early signal: drain own stores, add 1; consumers wait >= 8.
      asm volatile("s_waitcnt vmcnt(0)" ::: "memory");
      if (lane == 0)
        __hip_atomic_fetch_add(&flag0[(s * 48 + t) * FSTRIDE], 1,
                               __ATOMIC_RELAXED, __HIP_MEMORY_SCOPE_AGENT);
      __syncthreads();  // all waves done reading buf0/buf1
      // Refresh the persistent up-image for s+1 (block-internal, post-flag).
#pragma unroll
      for (int mt = 0; mt < 2; ++mt)
#pragma unroll
        for (int nt = 0; nt < 2; ++nt)
#pragma unroll
          for (int rr = 0; rr < 4; ++rr) {
            int row = mt * 16 + q * 4 + rr;
            *(short*)(buf0 + row * 528 + (n0 + nt * 16) * 2) =
                f2bf(hx[(mt * 2 + nt) * 4 + rr]);
          }
      __syncthreads();  // up-image ready for next s
    }
  } else {
    // ---- layer 1 ----
    const char* wb = ws + WF_OFF + (size_t)((2 + nh) * 4 + w) * 16384u +
                     (size_t)lane * 16;
    const float bsa = bvec[256 + n0], bsb = bvec[256 + n0 + 16];
    const f32x4 bA = {bsa, bsa, bsa, bsa};
    const f32x4 bB = {bsb, bsb, bsb, bsb};
    const f32x4 zf = {0.f, 0.f, 0.f, 0.f};
    for (int s = 0; s < 48; ++s) {
      f32x4 accx[2][2], accy[2][2], acc[2][2];
      accx[0][0] = bA; accx[0][1] = bB; accx[1][0] = bA; accx[1][1] = bB;
      accy[0][0] = bA; accy[0][1] = bB; accy[1][0] = bA; accy[1][1] = bB;
      acc[0][0] = zf; acc[0][1] = zf; acc[1][0] = zf; acc[1][1] = zf;

      // X/Y projections first: layer 0 runs ahead, so flag0 is usually set.
      wait_ge(&flag0[(s * 48 + t) * FSTRIDE], 8);
      {
        const float* px = out + plane_off(0, s, t, 0);
        const float* py = out + plane_off(0, s, t, 1);
#pragma unroll
        for (int it = 0; it < 4; ++it) {
          int gid = it * 512 + tid;
          int pidx = gid >> 10, row = (gid >> 5) & 31, c = gid & 31;
          const float* pp = pidx ? py : px;
          char* db = pidx ? buf2 : buf1;
          const float* p = pp + row * 256 + c * 8;
          short8 v;
#pragma unroll
          for (int j = 0; j < 8; ++j) v[j] = f2bf(p[j]);
          *(short8*)(db + row * 528 + c * 16) = v;
        }
      }
      __syncthreads();
      // accx += hx0@W1, accy += hy0@W1 (bw frags streamed from L1/L2-hot ws).
#pragma unroll
      for (int ks = 0; ks < 8; ++ks) {
        short8 b0 = *(const short8*)(wb + ks * 1024);
        short8 b1 = *(const short8*)(wb + (8 + ks) * 1024);
        short8 ax0 = *(const short8*)(l0 + ks * 64);
        short8 ax1 = *(const short8*)(l1 + ks * 64);
        short8 ay0 = *(const short8*)(y0 + ks * 64);
        short8 ay1 = *(const short8*)(y1 + ks * 64);
        accx[0][0] = MFMA16(ax0, b0, accx[0][0]);
        accx[0][1] = MFMA16(ax0, b1, accx[0][1]);
        accx[1][0] = MFMA16(ax1, b0, accx[1][0]);
        accx[1][1] = MFMA16(ax1, b1, accx[1][1]);
        accy[0][0] = MFMA16(ay0, b0, accy[0][0]);
        accy[0][1] = MFMA16(ay0, b1, accy[0][1]);
        accy[1][0] = MFMA16(ay1, b0, accy[1][0]);
        accy[1][1] = MFMA16(ay1, b1, accy[1][1]);
      }
      if (t > 0) wait_ge(&flag1[(s * 48 + (t - 1)) * FSTRIDE], 8);
      __syncthreads();  // projection reads of buf1 done before restage
      if (t > 0) {
        const float* pl = out + plane_off(1, s, t - 1, 0);
#pragma unroll
        for (int it = 0; it < 2; ++it) {
          int gid = it * 512 + tid;
          int row = gid >> 5, c = gid & 31;
          const float* p = pl + row * 256 + c * 8;
          short8 v;
#pragma unroll
          for (int j = 0; j < 8; ++j) v[j] = f2bf(p[j]);
          *(short8*)(buf1 + row * 528 + c * 16) = v;
        }
      }
      __syncthreads();
      // T = up1@Ux1 (+ left1@Uy1)
#pragma unroll
      for (int ks = 0; ks < 8; ++ks) {
        short8 a0 = *(const short8*)(up0 + ks * 64);
        short8 a1 = *(const short8*)(up1 + ks * 64);
        acc[0][0] = MFMA16(a0, bu[0][ks], acc[0][0]);
        acc[0][1] = MFMA16(a0, bu[1][ks], acc[0][1]);
        acc[1][0] = MFMA16(a1, bu[0][ks], acc[1][0]);
        acc[1][1] = MFMA16(a1, bu[1][ks], acc[1][1]);
      }
      if (t > 0) {
#pragma unroll
        for (int ks = 0; ks < 8; ++ks) {
          short8 a0 = *(const short8*)(l0 + ks * 64);
          short8 a1 = *(const short8*)(l1 + ks * 64);
          acc[0][0] = MFMA16(a0, bu[0][8 + ks], acc[0][0]);
          acc[0][1] = MFMA16(a0, bu[1][8 + ks], acc[0][1]);
          acc[1][0] = MFMA16(a1, bu[0][8 + ks], acc[1][0]);
          acc[1][1] = MFMA16(a1, bu[1][8 + ks], acc[1][1]);
        }
      }
      float hx[16];
      {
        float* hxp = out + plane_off(1, s, t, 0);
        float* hyp = out + plane_off(1, s, t, 1);
#pragma unroll
        for (int mt = 0; mt < 2; ++mt)
#pragma unroll
          for (int nt = 0; nt < 2; ++nt)
#pragma unroll
            for (int rr = 0; rr < 4; ++rr) {
              int row = mt * 16 + q * 4 + rr;
              int n = n0 + nt * 16;
              float tv = acc[mt][nt][rr];
              float xv = fast_tanh(accx[mt][nt][rr] + tv);
              float yv = fast_tanh(accy[mt][nt][rr] + tv);
              hx[(mt * 2 + nt) * 4 + rr] = xv;
              st_llc(&hxp[row * 256 + n], xv);  // consumed by right neighbor
              hyp[row * 256 + n] = yv;          // final output only
            }
      }
      asm volatile("s_waitcnt vmcnt(0)" ::: "memory");
      if (lane == 0)
        __hip_atomic_fetch_add(&flag1[(s * 48 + t) * FSTRIDE], 1,
                               __ATOMIC_RELAXED, __HIP_MEMORY_SCOPE_AGENT);
      __syncthreads();  // all waves done reading buf0/buf1
#pragma unroll
      for (int mt = 0; mt < 2; ++mt)
#pragma unroll
        for (int nt = 0; nt < 2; ++nt)
#pragma unroll
          for (int rr = 0; rr < 4; ++rr) {
            int row = mt * 16 + q * 4 + rr;
            *(short*)(buf0 + row * 528 + (n0 + nt * 16) * 2) =
                f2bf(hx[(mt * 2 + nt) * 4 + rr]);
          }
      __syncthreads();  // up-image ready for next s
    }
  }
}

extern "C" void kernel_launch(void* const* d_in, const int* in_sizes, int n_in,
                              void* d_out, int out_size, void* d_ws, size_t ws_size,
                              hipStream_t stream) {
  const float* src = (const float*)d_in[0];
  const float* trg = (const float*)d_in[1];
  const float* W   = (const float*)d_in[2];
  const float* U   = (const float*)d_in[3];
  const float* bv  = (const float*)d_in[4];
  float* out = (float*)d_out;
  char* ws = (char*)d_ws;

  hipMemsetAsync(ws + FLAG0_OFF, 0, 2u * 48 * 48 * 128, stream);
  preswizzle<<<192, 256, 0, stream>>>(U, W, ws);
  precompute_xw<<<192, 256, 0, stream>>>(src, trg, bv, ws);
  grid_main<<<96, 512, 0, stream>>>(out, bv, ws);
}